// Round 2
// 2995.948 us; speedup vs baseline: 1.0446x; 1.0446x over previous
//
#include <hip/hip_runtime.h>
#include <math.h>

// Problem constants (fixed by the harness).
#define BB 4096
#define TT 2048
#define LL 100

constexpr int NB = 16;       // batch items per block (= MFMA M)
constexpr int WG = 448;      // 7 waves, ALL layer-1; wave 3 also carries layer-2
constexpr int XTILE = 64;    // input timesteps staged per LDS tile
constexpr int XSTR = 20;     // xs_t row stride (dwords)

#define L2E 1.44269504088896340736f

// Split-plane A-frag layout: hi and lo bf16 planes in separate LDS arrays,
// each phase 4 kt x 64 rows x 4 dwords (bf16x8 fragment per (kt,row)).
// Granule (16B) index = kt*64 + (row ^ (row>>3)); the XOR makes BOTH the
// b128 reads (row = lane) and the per-item dword scatter writes hit all 32
// banks exactly once. No perm unpack on the read side: fragments feed MFMA
// directly, and the lo-plane reads are deferred behind 32 MFMAs.
#define AH(kt, row) (((kt) * 64 + ((row) ^ ((row) >> 3))) * 4)

typedef short bf16x8 __attribute__((ext_vector_type(8)));
typedef float f32x4 __attribute__((ext_vector_type(4)));

union AF { int4 v; bf16x8 f; unsigned int w[4]; };

__device__ __forceinline__ unsigned int bf16rn(float x) {  // fp32 -> bf16 RNE
    unsigned int u = __float_as_uint(x);
    u += 0x7fffu + ((u >> 16) & 1u);
    return u >> 16;
}
__device__ __forceinline__ float bf16f(unsigned int h) { return __uint_as_float(h << 16); }
__device__ __forceinline__ float frcp(float x) { return __builtin_amdgcn_rcpf(x); }
__device__ __forceinline__ float fexp2(float x) {
#if __has_builtin(__builtin_amdgcn_exp2f)
    return __builtin_amdgcn_exp2f(x);
#else
    return exp2f(x);
#endif
}
// log2e pre-folded into weights/biases (v_exp_f32 IS 2^x).
__device__ __forceinline__ float sig2(float xp) { return frcp(1.0f + fexp2(-xp)); }
__device__ __forceinline__ float th2(float xpp) { return 1.0f - 2.0f * frcp(1.0f + fexp2(xpp)); }
__device__ __forceinline__ float ftanh_n(float x) { return th2(2.0f * L2E * x); }

__device__ __forceinline__ unsigned int perm_lo(unsigned int w0, unsigned int w1) {
#if __has_builtin(__builtin_amdgcn_perm)
    return __builtin_amdgcn_perm(w1, w0, 0x05040100u);
#else
    return (w0 & 0xffffu) | (w1 << 16);
#endif
}
__device__ __forceinline__ unsigned int perm_hi(unsigned int w0, unsigned int w1) {
#if __has_builtin(__builtin_amdgcn_perm)
    return __builtin_amdgcn_perm(w1, w0, 0x07060302u);
#else
    return (w0 >> 16) | (w1 & 0xffff0000u);
#endif
}
__device__ __forceinline__ unsigned int xor1_lane(unsigned int v) {
#if __has_builtin(__builtin_amdgcn_mov_dpp)
    // quad_perm [1,0,3,2] = lane^1 exchange, pure VALU (no LDS pipe traffic)
    return (unsigned int)__builtin_amdgcn_mov_dpp((int)v, 0xB1, 0xF, 0xF, false);
#else
    return (unsigned int)__shfl_xor((int)v, 1, 64);
#endif
}

// Layer-1: gates padded 100->112 unit-slots; wave w owns all 4 gates of one
// 16-slot group. Slot-group permutation {0,1,2,6,3,4,5} puts the PAD group
// (slots 96..111) on wave 3 (solo on SIMD3). Layer-2 rides in the pad:
// B-column col16==8 of wave 3 holds W_ih2[g]; the MFMA D-frag hands lane
// (w3,c8,quad) the layer-2 preacts of items 4*quad..4*quad+3 (one step
// behind). Biases stay EXACT fp32 scalar adds (bs/bs2s): folding them into
// the bf16-split MFMA (R1) lost ~2^-16 rel/step systematically and the
// c2 recurrence amplified it to 4e-3 absmax -> fail. Do not re-fold.
// Frag layouts (HW-verified R4-R6): A[m=lane&15][k=32kt+8quad+j];
// B[k][n=lane&15]; D col=lane&15, row=quad*4+reg.
__global__ void __launch_bounds__(WG)
__attribute__((amdgpu_waves_per_eu(2, 2)))
lstm2_kernel(const float* __restrict__ input,   // [B,T]
             const float* __restrict__ W_ih1,   // [400,1]
             const float* __restrict__ W_hh1,   // [400,100]
             const float* __restrict__ b_ih1,   // [400]
             const float* __restrict__ b_hh1,   // [400]
             const float* __restrict__ W_ih2,   // [4,100]
             const float* __restrict__ W_hh2,   // [4,1]
             const float* __restrict__ b_ih2,   // [4]
             const float* __restrict__ b_hh2,   // [4]
             float* __restrict__ out)           // [B,T]
{
    __shared__ __align__(16) unsigned int afragH[2][1024];   // 8 KB hi-bf16 plane
    __shared__ __align__(16) unsigned int afragL[2][1024];   // 8 KB lo-bf16 plane
    __shared__ __align__(16) float xs_t[XTILE][XSTR];        // 5.1 KB transposed input

    const int tid = threadIdx.x;
    const int wave = tid >> 6;       // 0..6
    const int lane = tid & 63;
    const int col16 = lane & 15;
    const int quad = lane >> 4;
    const int bg0 = blockIdx.x * NB;

    // ---------------- init ----------------
    for (int i = tid; i < 2 * 1024; i += WG) {
        (&afragH[0][0])[i] = 0u;
        (&afragL[0][0])[i] = 0u;
    }

    // slot-group permutation: wave 3 -> group 6 (slots 96..111)
    const int sb = (wave == 3) ? 6 : ((wave < 3) ? wave : wave - 1);
    const int uu = 16 * sb + col16;          // unit-slot owned by this lane
    const bool uvalid = (uu < LL);           // pad slots produce h=0
    const bool l2lane = (wave == 3) && (col16 == 8);   // layer-2 carrier lanes

    // gate scales folding log2e (i,f,o: sigmoid; g: tanh needs 2x)
    const float gsc[4] = {L2E, L2E, 2.0f * L2E, L2E};

    // Persistent B-fragments: bf16 hi/mid splits of scaled weights.
    // Normal lanes: W_hh1 rows; (w3,c8) lanes: W_ih2 rows (layer-2 in pad column).
    bf16x8 bhi[4][4], bmid[4][4];
#pragma unroll
    for (int g = 0; g < 4; ++g)
#pragma unroll
        for (int kt = 0; kt < 4; ++kt)
#pragma unroll
            for (int j = 0; j < 8; ++j) {
                const int k = 32 * kt + 8 * quad + j;
                float w = 0.0f;
                if (k < LL) {
                    if (l2lane)       w = W_ih2[g * LL + k] * gsc[g];
                    else if (uvalid)  w = W_hh1[(100 * g + uu) * LL + k] * gsc[g];
                }
                const unsigned int hh = bf16rn(w);
                bhi[g][kt][j] = (short)hh;
                bmid[g][kt][j] = (short)bf16rn(w - bf16f(hh));
            }

    float wx[4], bs[4];
    float c1[4] = {0.f, 0.f, 0.f, 0.f};
#pragma unroll
    for (int g = 0; g < 4; ++g) {
        wx[g] = uvalid ? W_ih1[100 * g + uu] * gsc[g] : 0.0f;
        bs[g] = uvalid ? (b_ih1[100 * g + uu] + b_hh1[100 * g + uu]) * gsc[g] : 0.0f;
    }

    const int kt_u = uu >> 5;
    const int lnb = ((uu >> 3) & 3) * 16;
    const int jh = (uu & 7) >> 1;
    const bool oddu = (uu & 1) != 0;

    // Layer-2 recurrent state (l2lane only; 4 items per lane, m = 4*quad+r)
    float wh2s[4], bs2s[4], h2v[4] = {0.f, 0.f, 0.f, 0.f}, c2v[4] = {0.f, 0.f, 0.f, 0.f};
#pragma unroll
    for (int g = 0; g < 4; ++g) {
        wh2s[g] = l2lane ? W_hh2[g] * gsc[g] : 0.0f;
        bs2s[g] = l2lane ? (b_ih2[g] + b_hh2[g]) * gsc[g] : 0.0f;
    }

    __syncthreads();

    // ---------------- time loop (one barrier per step) ----------------
    for (int t = 0; t <= TT; ++t) {
        const int p = t & 1, pn = p ^ 1;

        if (t < TT && (t & (XTILE - 1)) == 0) {
            for (int i = tid; i < NB * XTILE; i += WG) {
                const int m = i >> 6, t2 = i & (XTILE - 1);
                xs_t[t2][m] = input[(size_t)(bg0 + m) * TT + t + t2];
            }
            __syncthreads();
        }

        // wave 3 also runs at t==TT to produce the final layer-2 output
        if (t < TT || wave == 3) {
            // ---- hi-plane A-frags (h1_{t-1} hi bf16): direct b128 -> MFMA ----
            AF ahi[4];
#pragma unroll
            for (int kt = 0; kt < 4; ++kt)
                ahi[kt].v = *(const int4*)&afragH[p][AH(kt, lane)];

            f32x4 acc[4];
#pragma unroll
            for (int g = 0; g < 4; ++g) acc[g] = (f32x4){0.f, 0.f, 0.f, 0.f};

            // pass 1: ahi * bhi
#pragma unroll
            for (int kt = 0; kt < 4; ++kt)
#pragma unroll
                for (int g = 0; g < 4; ++g)
                    acc[g] = __builtin_amdgcn_mfma_f32_16x16x32_bf16(ahi[kt].f, bhi[g][kt], acc[g], 0, 0, 0);
            // pass 2: ahi * bmid (only needs ahi -> covers the alo load latency)
#pragma unroll
            for (int kt = 0; kt < 4; ++kt)
#pragma unroll
                for (int g = 0; g < 4; ++g)
                    acc[g] = __builtin_amdgcn_mfma_f32_16x16x32_bf16(ahi[kt].f, bmid[g][kt], acc[g], 0, 0, 0);

            // ---- lo-plane A-frags, deferred ----
            AF alo[4];
#pragma unroll
            for (int kt = 0; kt < 4; ++kt)
                alo[kt].v = *(const int4*)&afragL[p][AH(kt, lane)];
            // pass 3: alo * bhi
#pragma unroll
            for (int kt = 0; kt < 4; ++kt)
#pragma unroll
                for (int g = 0; g < 4; ++g)
                    acc[g] = __builtin_amdgcn_mfma_f32_16x16x32_bf16(alo[kt].f, bhi[g][kt], acc[g], 0, 0, 0);

            // ---- layer 2 (l2lane): acc[g][r] = dot(W_ih2[g], h1_{t-1}[4q+r]) ----
            if (l2lane && t >= 1) {
#pragma unroll
                for (int r = 0; r < 4; ++r) {
                    const float p0 = acc[0][r] + fmaf(wh2s[0], h2v[r], bs2s[0]);
                    const float p1 = acc[1][r] + fmaf(wh2s[1], h2v[r], bs2s[1]);
                    const float p2 = acc[2][r] + fmaf(wh2s[2], h2v[r], bs2s[2]);
                    const float p3 = acc[3][r] + fmaf(wh2s[3], h2v[r], bs2s[3]);
                    const float i2 = sig2(p0), f2 = sig2(p1), g2 = th2(p2), o2 = sig2(p3);
                    c2v[r] = f2 * c2v[r] + i2 * g2;
                    h2v[r] = o2 * ftanh_n(c2v[r]);
                    out[(size_t)(bg0 + 4 * quad + r) * TT + (t - 1)] = h2v[r];
                }
            }

            // ---- layer-1 cell update + split-plane h write-back ----
            if (t < TT) {
                const float4 x4 = *(const float4*)&xs_t[t & (XTILE - 1)][4 * quad];
                const float xr[4] = {x4.x, x4.y, x4.z, x4.w};
                unsigned int* const wpl = oddu ? afragL[pn] : afragH[pn];
#pragma unroll
                for (int r = 0; r < 4; ++r) {
                    const int m = 4 * quad + r;
                    const float gi = acc[0][r] + fmaf(wx[0], xr[r], bs[0]);
                    const float gf = acc[1][r] + fmaf(wx[1], xr[r], bs[1]);
                    const float gG = acc[2][r] + fmaf(wx[2], xr[r], bs[2]);
                    const float go = acc[3][r] + fmaf(wx[3], xr[r], bs[3]);
                    const float iv = sig2(gi);
                    const float fv = sig2(gf);
                    const float gv = th2(gG);
                    const float ov = sig2(go);
                    const float c = fv * c1[r] + iv * gv;
                    c1[r] = c;
                    const float h = uvalid ? (ov * ftanh_n(c)) : 0.0f;  // pads stay 0
                    const unsigned int hh = bf16rn(h);
                    const unsigned int hl = bf16rn(h - bf16f(hh));
                    const unsigned int P = hh | (hl << 16);
                    const unsigned int Q = xor1_lane(P);   // partner unit's (hh|hl)
                    // even unit -> hi-plane dword (hh_e | hh_o<<16)
                    // odd  unit -> lo-plane dword (hl_e | hl_o<<16)
                    wpl[AH(kt_u, lnb + m) + jh] = oddu ? perm_hi(Q, P) : perm_lo(P, Q);
                }
            }
        }

        __syncthreads();   // h1_t (afragH/L[pn]) visible for step t+1
    }
}

extern "C" void kernel_launch(void* const* d_in, const int* in_sizes, int n_in,
                              void* d_out, int out_size, void* d_ws, size_t ws_size,
                              hipStream_t stream) {
    const float* input = (const float*)d_in[0];
    const float* W_ih1 = (const float*)d_in[1];
    const float* W_hh1 = (const float*)d_in[2];
    const float* b_ih1 = (const float*)d_in[3];
    const float* b_hh1 = (const float*)d_in[4];
    const float* W_ih2 = (const float*)d_in[5];
    const float* W_hh2 = (const float*)d_in[6];
    const float* b_ih2 = (const float*)d_in[7];
    const float* b_hh2 = (const float*)d_in[8];
    float* out = (float*)d_out;

    dim3 grid(BB / NB);   // 256 workgroups -> 1 per CU
    dim3 block(WG);       // 448 threads = 7 waves
    lstm2_kernel<<<grid, block, 0, stream>>>(input, W_ih1, W_hh1, b_ih1, b_hh1,
                                             W_ih2, W_hh2, b_ih2, b_hh2, out);
}

// Round 3
// 2739.138 us; speedup vs baseline: 1.1426x; 1.0938x over previous
//
#include <hip/hip_runtime.h>
#include <math.h>

// Problem constants (fixed by the harness).
#define BB 4096
#define TT 2048
#define LL 100

constexpr int NB = 16;       // batch items per block (= MFMA M)
constexpr int WG = 448;      // 7 waves, ALL layer-1; wave 3 also carries layer-2

#define L2E 1.44269504088896340736f

// Split-plane A-frag layout: hi and lo bf16 planes in separate LDS arrays,
// each phase 4 kt x 64 rows x 4 dwords (bf16x8 fragment per (kt,row)).
// Granule (16B) index = kt*64 + (row ^ (row>>3)); XOR makes BOTH the b128
// reads (row = lane) and the per-item dword scatter writes conflict-free.
#define AH(kt, row) (((kt) * 64 + ((row) ^ ((row) >> 3))) * 4)

typedef short bf16x8 __attribute__((ext_vector_type(8)));
typedef float f32x4 __attribute__((ext_vector_type(4)));

union AF { int4 v; bf16x8 f; unsigned int w[4]; };

__device__ __forceinline__ float frcp(float x) { return __builtin_amdgcn_rcpf(x); }
__device__ __forceinline__ float fexp2(float x) {
#if __has_builtin(__builtin_amdgcn_exp2f)
    return __builtin_amdgcn_exp2f(x);
#else
    return exp2f(x);
#endif
}
// log2e pre-folded into weights/biases (v_exp_f32 IS 2^x).
__device__ __forceinline__ float sig2(float xp) { return frcp(1.0f + fexp2(-xp)); }
__device__ __forceinline__ float th2(float xpp) { return 1.0f - 2.0f * frcp(1.0f + fexp2(xpp)); }
__device__ __forceinline__ float ftanh_n(float x) { return th2(2.0f * L2E * x); }

__device__ __forceinline__ unsigned int xor1_lane(unsigned int v) {
#if __has_builtin(__builtin_amdgcn_mov_dpp)
    // quad_perm [1,0,3,2] = lane^1 exchange, pure VALU (no LDS pipe traffic)
    return (unsigned int)__builtin_amdgcn_mov_dpp((int)v, 0xB1, 0xF, 0xF, false);
#else
    return (unsigned int)__shfl_xor((int)v, 1, 64);
#endif
}
__device__ __forceinline__ unsigned int cvt_pk_bf16(float lo, float hi) {
    unsigned int d;
    asm("v_cvt_pk_bf16_f32 %0, %1, %2" : "=v"(d) : "v"(lo), "v"(hi));
    return d;
}

// Layer-1: gates padded 100->112 unit-slots; wave w owns all 4 gates of one
// 16-slot group. Slot-group permutation {0,1,2,6,3,4,5} puts the PAD group
// (slots 96..111) on wave 3 (solo on SIMD3). Layer-2 rides in the pad:
// B-column col16==8 of wave 3 holds W_ih2[g].
// R3 folds (all exact-fp32-safe, unlike R1's bf16 bias fold):
//  - biases enter as the MFMA C-input (binit), bit-exact fp32;
//  - x_t rides A-column k=100 (pad lanes uu=100/101 deposit x_{t+1} each
//    step; B-row k=100 = W_ih1 hi+mid split). xs staging/LDS/barrier gone;
//    x loads come straight from global (L1-resident) on 4 wave-3 lanes.
//  - pack via v_cvt_pk_bf16_f32 (lo plane self-compensates any rounding).
// Frag layouts (HW-verified R4-R6): A[m=lane&15][k=32kt+8quad+j];
// B[k][n=lane&15]; D col=lane&15, row=quad*4+reg.
__global__ void __launch_bounds__(WG)
__attribute__((amdgpu_waves_per_eu(2, 2)))
lstm2_kernel(const float* __restrict__ input,   // [B,T]
             const float* __restrict__ W_ih1,   // [400,1]
             const float* __restrict__ W_hh1,   // [400,100]
             const float* __restrict__ b_ih1,   // [400]
             const float* __restrict__ b_hh1,   // [400]
             const float* __restrict__ W_ih2,   // [4,100]
             const float* __restrict__ W_hh2,   // [4,1]
             const float* __restrict__ b_ih2,   // [4]
             const float* __restrict__ b_hh2,   // [4]
             float* __restrict__ out)           // [B,T]
{
    __shared__ __align__(16) unsigned int afragH[2][1024];   // 8 KB hi-bf16 plane
    __shared__ __align__(16) unsigned int afragL[2][1024];   // 8 KB lo-bf16 plane

    const int tid = threadIdx.x;
    const int wave = tid >> 6;       // 0..6
    const int lane = tid & 63;
    const int col16 = lane & 15;
    const int quad = lane >> 4;
    const int bg0 = blockIdx.x * NB;

    // ---------------- init ----------------
    for (int i = tid; i < 2 * 1024; i += WG) {
        (&afragH[0][0])[i] = 0u;
        (&afragL[0][0])[i] = 0u;
    }

    // slot-group permutation: wave 3 -> group 6 (slots 96..111)
    const int sb = (wave == 3) ? 6 : ((wave < 3) ? wave : wave - 1);
    const int uu = 16 * sb + col16;          // unit-slot owned by this lane
    const bool uvalid = (uu < LL);           // pad slots produce h=0
    const bool l2lane = (wave == 3) && (col16 == 8);   // layer-2 carrier lanes
    const bool xlane = (wave == 3) && (col16 == 4);    // x-depositor lanes (uu==100)

    // gate scales folding log2e (i,f,o: sigmoid; g: tanh needs 2x)
    const float gsc[4] = {L2E, L2E, 2.0f * L2E, L2E};

    // Persistent B-fragments: bf16 hi/mid splits of scaled weights.
    // Normal lanes: W_hh1 rows (+ W_ih1 at k==100); l2lane: W_ih2 rows.
    bf16x8 bhi[4][4], bmid[4][4];
#pragma unroll
    for (int g = 0; g < 4; ++g)
#pragma unroll
        for (int kt = 0; kt < 4; ++kt)
#pragma unroll
            for (int j = 0; j < 8; ++j) {
                const int k = 32 * kt + 8 * quad + j;
                float w = 0.0f;
                if (k < LL) {
                    if (l2lane)       w = W_ih2[g * LL + k] * gsc[g];
                    else if (uvalid)  w = W_hh1[(100 * g + uu) * LL + k] * gsc[g];
                } else if (k == 100) {
                    if (!l2lane && uvalid) w = W_ih1[100 * g + uu] * gsc[g];
                }
                const unsigned int hh = cvt_pk_bf16(w, 0.0f) & 0xffffu;
                bhi[g][kt][j] = (short)hh;
                const float wres = w - __uint_as_float(hh << 16);
                bmid[g][kt][j] = (short)(cvt_pk_bf16(wres, 0.0f) & 0xffffu);
            }

    // Exact fp32 biases as the MFMA C-input (same value in all 4 D-rows of
    // this lane's column). l2lane gets layer-2 bias; pads get 0.
    f32x4 binit[4];
#pragma unroll
    for (int g = 0; g < 4; ++g) {
        float bv = 0.0f;
        if (l2lane)      bv = (b_ih2[g] + b_hh2[g]) * gsc[g];
        else if (uvalid) bv = (b_ih1[100 * g + uu] + b_hh1[100 * g + uu]) * gsc[g];
        binit[g] = (f32x4){bv, bv, bv, bv};
    }

    float c1[4] = {0.f, 0.f, 0.f, 0.f};

    const int kt_u = uu >> 5;
    const int lnb = ((uu >> 3) & 3) * 16;
    const int jh = (uu & 7) >> 1;
    const bool oddu = (uu & 1) != 0;

    // Layer-2 recurrent state (l2lane only; 4 items per lane, m = 4*quad+r)
    float wh2s[4], h2v[4] = {0.f, 0.f, 0.f, 0.f}, c2v[4] = {0.f, 0.f, 0.f, 0.f};
#pragma unroll
    for (int g = 0; g < 4; ++g)
        wh2s[g] = l2lane ? W_hh2[g] * gsc[g] : 0.0f;

    __syncthreads();

    // ---- prologue: deposit x_0 into the k=100 column of phase 0 ----
    if (wave == 3 && (col16 == 4 || col16 == 5)) {
#pragma unroll
        for (int r = 0; r < 4; ++r) {
            const int m = 4 * quad + r;
            const float h = (col16 == 4) ? input[(size_t)(bg0 + m) * TT] : 0.0f;
            const float hq = __uint_as_float(xor1_lane(__float_as_uint(h)));
            const unsigned int tpk = cvt_pk_bf16(h, hq);
            const float hl_own = h - __uint_as_float(tpk << 16);
            const float hl_par = hq - __uint_as_float(tpk & 0xffff0000u);
            const unsigned int lod = cvt_pk_bf16(hl_par, hl_own);
            (oddu ? afragL[0] : afragH[0])[AH(kt_u, lnb + m) + jh] = oddu ? lod : tpk;
        }
    }
    __syncthreads();

    // ---------------- time loop (one barrier per step) ----------------
    for (int t = 0; t <= TT; ++t) {
        const int p = t & 1, pn = p ^ 1;

        // wave 3 also runs at t==TT to produce the final layer-2 output
        if (t < TT || wave == 3) {
            // x_{t+1} prefetch (4 lanes of wave 3; L1-resident lines).
            float xnext[4] = {0.f, 0.f, 0.f, 0.f};
            if (xlane && t + 1 < TT) {
#pragma unroll
                for (int r = 0; r < 4; ++r)
                    xnext[r] = input[(size_t)(bg0 + 4 * quad + r) * TT + (t + 1)];
            }

            // ---- hi-plane A-frags (h1_{t-1} hi bf16): direct b128 -> MFMA ----
            AF ahi[4];
#pragma unroll
            for (int kt = 0; kt < 4; ++kt)
                ahi[kt].v = *(const int4*)&afragH[p][AH(kt, lane)];

            // pass 1: ahi * bhi, bias preloaded via C
            f32x4 acc[4];
#pragma unroll
            for (int g = 0; g < 4; ++g)
                acc[g] = __builtin_amdgcn_mfma_f32_16x16x32_bf16(ahi[0].f, bhi[g][0], binit[g], 0, 0, 0);
#pragma unroll
            for (int kt = 1; kt < 4; ++kt)
#pragma unroll
                for (int g = 0; g < 4; ++g)
                    acc[g] = __builtin_amdgcn_mfma_f32_16x16x32_bf16(ahi[kt].f, bhi[g][kt], acc[g], 0, 0, 0);
            // pass 2: ahi * bmid (only needs ahi -> covers the alo load latency)
#pragma unroll
            for (int kt = 0; kt < 4; ++kt)
#pragma unroll
                for (int g = 0; g < 4; ++g)
                    acc[g] = __builtin_amdgcn_mfma_f32_16x16x32_bf16(ahi[kt].f, bmid[g][kt], acc[g], 0, 0, 0);

            // ---- lo-plane A-frags, deferred ----
            AF alo[4];
#pragma unroll
            for (int kt = 0; kt < 4; ++kt)
                alo[kt].v = *(const int4*)&afragL[p][AH(kt, lane)];
            // pass 3: alo * bhi
#pragma unroll
            for (int kt = 0; kt < 4; ++kt)
#pragma unroll
                for (int g = 0; g < 4; ++g)
                    acc[g] = __builtin_amdgcn_mfma_f32_16x16x32_bf16(alo[kt].f, bhi[g][kt], acc[g], 0, 0, 0);

            // ---- layer 2 (l2lane): acc[g][r] = b2 + dot(W_ih2[g], h1_{t-1}[4q+r]) ----
            if (l2lane && t >= 1) {
#pragma unroll
                for (int r = 0; r < 4; ++r) {
                    const float p0 = fmaf(wh2s[0], h2v[r], acc[0][r]);
                    const float p1 = fmaf(wh2s[1], h2v[r], acc[1][r]);
                    const float p2 = fmaf(wh2s[2], h2v[r], acc[2][r]);
                    const float p3 = fmaf(wh2s[3], h2v[r], acc[3][r]);
                    const float i2 = sig2(p0), f2 = sig2(p1), g2 = th2(p2), o2 = sig2(p3);
                    c2v[r] = f2 * c2v[r] + i2 * g2;
                    h2v[r] = o2 * ftanh_n(c2v[r]);
                    out[(size_t)(bg0 + 4 * quad + r) * TT + (t - 1)] = h2v[r];
                }
            }

            // ---- layer-1 cell update + split-plane h write-back ----
            if (t < TT) {
                unsigned int* const wpl = oddu ? afragL[pn] : afragH[pn];
#pragma unroll
                for (int r = 0; r < 4; ++r) {
                    const int m = 4 * quad + r;
                    // bias and x already inside acc -> gates are acc directly
                    const float iv = sig2(acc[0][r]);
                    const float fv = sig2(acc[1][r]);
                    const float gv = th2(acc[2][r]);
                    const float ov = sig2(acc[3][r]);
                    const float c = fv * c1[r] + iv * gv;
                    c1[r] = c;
                    // valid units: h; pad lanes: 0 except uu==100 carries x_{t+1}
                    const float h = uvalid ? (ov * ftanh_n(c)) : xnext[r];
                    // pair-pack via DPP + cvt_pk: even lane emits hi-plane dword
                    // (hh_e|hh_o), odd lane emits lo-plane dword (hl_e|hl_o).
                    // lo plane self-compensates cvt_pk's rounding of the hi.
                    const float hq = __uint_as_float(xor1_lane(__float_as_uint(h)));
                    const unsigned int tpk = cvt_pk_bf16(h, hq);
                    const float hl_own = h - __uint_as_float(tpk << 16);
                    const float hl_par = hq - __uint_as_float(tpk & 0xffff0000u);
                    const unsigned int lod = cvt_pk_bf16(hl_par, hl_own);
                    wpl[AH(kt_u, lnb + m) + jh] = oddu ? lod : tpk;
                }
            }
        }

        __syncthreads();   // h1_t (afragH/L[pn]) visible for step t+1
    }
}

extern "C" void kernel_launch(void* const* d_in, const int* in_sizes, int n_in,
                              void* d_out, int out_size, void* d_ws, size_t ws_size,
                              hipStream_t stream) {
    const float* input = (const float*)d_in[0];
    const float* W_ih1 = (const float*)d_in[1];
    const float* W_hh1 = (const float*)d_in[2];
    const float* b_ih1 = (const float*)d_in[3];
    const float* b_hh1 = (const float*)d_in[4];
    const float* W_ih2 = (const float*)d_in[5];
    const float* W_hh2 = (const float*)d_in[6];
    const float* b_ih2 = (const float*)d_in[7];
    const float* b_hh2 = (const float*)d_in[8];
    float* out = (float*)d_out;

    dim3 grid(BB / NB);   // 256 workgroups -> 1 per CU
    dim3 block(WG);       // 448 threads = 7 waves
    lstm2_kernel<<<grid, block, 0, stream>>>(input, W_ih1, W_hh1, b_ih1, b_hh1,
                                             W_ih2, W_hh2, b_ih2, b_hh2, out);
}